// Round 2
// baseline (674.012 us; speedup 1.0000x reference)
//
#include <hip/hip_runtime.h>
#include <hip/hip_bf16.h>

#define NN 50000
#define EE 640000
#define HD 128
#define NCLS 40
#define BN_EPS 1e-5f

// ---------------- edge_index width detect + decode ----------------
__global__ void detect_kernel(const void* __restrict__ ei, int* __restrict__ flag) {
    // If buffer is int64: all sampled values in [0, NN). If it is int32, an
    // int64 reinterpret combines two int32 edge ids -> almost surely >= NN.
    int t = threadIdx.x;  // 256
    const long long* p = (const long long*)ei;
    long long v = p[(size_t)t * (EE / 256)];
    if (v < 0 || v >= NN) atomicOr(flag, 1);  // flag=1 -> int32 data
}

__global__ void decode_kernel(const void* __restrict__ ei, const int* __restrict__ flag,
                              int* __restrict__ src, int* __restrict__ dst) {
    bool narrow = (*flag != 0);
    for (int e = blockIdx.x * blockDim.x + threadIdx.x; e < EE; e += gridDim.x * blockDim.x) {
        if (narrow) {
            const int* p = (const int*)ei;
            src[e] = p[e];
            dst[e] = p[EE + e];
        } else {
            const long long* p = (const long long*)ei;
            src[e] = (int)p[e];
            dst[e] = (int)p[EE + e];
        }
    }
}

// ---------------- graph build ----------------
__global__ void deg_kernel(const int* __restrict__ dst, int* __restrict__ deg) {
    for (int e = blockIdx.x * blockDim.x + threadIdx.x; e < EE; e += gridDim.x * blockDim.x)
        atomicAdd(&deg[dst[e]], 1);
}

__global__ __launch_bounds__(1024) void scan_kernel(const int* __restrict__ deg,
                                                    int* __restrict__ rowptr,
                                                    float* __restrict__ invdeg) {
    __shared__ int part[1024];
    int t = threadIdx.x;
    const int CH = (NN + 1023) / 1024;  // 49
    int beg = t * CH;
    int end = beg + CH; if (end > NN) end = NN;
    int s = 0;
    for (int n = beg; n < end; ++n) s += deg[n];
    part[t] = s;
    __syncthreads();
    for (int off = 1; off < 1024; off <<= 1) {
        int v = (t >= off) ? part[t - off] : 0;
        __syncthreads();
        part[t] += v;
        __syncthreads();
    }
    int run = part[t] - s;  // exclusive prefix
    for (int n = beg; n < end; ++n) {
        rowptr[n] = run;
        int d = deg[n];
        run += d;
        invdeg[n] = 1.0f / (float)(d > 1 ? d : 1);
    }
    if (t == 1023) rowptr[NN] = part[1023];
}

__global__ void fill_kernel(const int* __restrict__ src, const int* __restrict__ dst,
                            const int* __restrict__ rowptr, int* __restrict__ cursor,
                            int* __restrict__ adj) {
    for (int e = blockIdx.x * blockDim.x + threadIdx.x; e < EE; e += gridDim.x * blockDim.x) {
        int d = dst[e];
        int pos = atomicAdd(&cursor[d], 1);
        adj[rowptr[d] + pos] = src[e];
    }
}

// ---------------- combined weights: Wc[which] = W_w @ lin_{l/r}[layer] ----------------
__global__ void combine_w(const float* __restrict__ Ww, const float* __restrict__ linl,
                          const float* __restrict__ linr, float* __restrict__ Wc) {
    int k = threadIdx.x;        // 0..127
    int m = blockIdx.x;         // 0..127
    int which = blockIdx.y;     // 0..3 : layer = which>>1, l/r = which&1
    const float* lin = ((which & 1) ? linr : linl) + (which >> 1) * HD * HD;
    __shared__ float wrow[HD];
    wrow[k] = Ww[m * HD + k];
    __syncthreads();
    float acc = 0.f;
    for (int j = 0; j < HD; ++j) acc += wrow[j] * lin[j * HD + k];
    Wc[which * HD * HD + m * HD + k] = acc;
}

// ---------------- GEMM: Y[n,m] = sum_k X[n,k]*W[m,k] (+bias) (+=Y) (+stats) ----------------
template <bool ACC, bool STATS>
__global__ __launch_bounds__(256) void gemm128(const float* __restrict__ X,
                                               const float* __restrict__ W,
                                               const float* __restrict__ bias,
                                               float* __restrict__ Y,
                                               float* __restrict__ stats) {
    __shared__ float wlds[HD * 132];
    __shared__ float xlds[8 * HD];
    __shared__ float bsum[256], bsq[256];
    int t = threadIdx.x;
    for (int j = t; j < HD * HD; j += 256) {
        int m = j >> 7, k = j & 127;
        wlds[m * 132 + k] = W[j];
    }
    int m = t & 127, rh = t >> 7;
    float bv = bias ? bias[m] : 0.f;
    __syncthreads();
    float ssum = 0.f, ssq = 0.f;
    const int NT = NN / 8;  // 6250
    for (int tile = blockIdx.x; tile < NT; tile += gridDim.x) {
        int r0 = tile * 8;
        __syncthreads();
        for (int j = t; j < 8 * HD; j += 256) xlds[j] = X[r0 * HD + j];
        __syncthreads();
        float acc[4] = {0.f, 0.f, 0.f, 0.f};
#pragma unroll
        for (int kk = 0; kk < HD; kk += 4) {
            float4 w = *reinterpret_cast<float4*>(&wlds[m * 132 + kk]);
#pragma unroll
            for (int r = 0; r < 4; ++r) {
                float4 xv = *reinterpret_cast<float4*>(&xlds[(rh * 4 + r) * HD + kk]);
                acc[r] += w.x * xv.x + w.y * xv.y + w.z * xv.z + w.w * xv.w;
            }
        }
#pragma unroll
        for (int r = 0; r < 4; ++r) {
            int row = r0 + rh * 4 + r;
            float y = acc[r] + bv;
            float* yp = &Y[row * HD + m];
            if (ACC) y += *yp;
            *yp = y;
            if (STATS) { ssum += y; ssq += y * y; }
        }
    }
    if (STATS) {
        bsum[t] = ssum; bsq[t] = ssq;
        __syncthreads();
        if (t < 128) {
            atomicAdd(&stats[t], bsum[t] + bsum[t + 128]);
            atomicAdd(&stats[128 + t], bsq[t] + bsq[t + 128]);
        }
    }
}

// ---------------- BN fold + apply ----------------
__global__ void bn_fold(const float* __restrict__ stats, const float* __restrict__ scale,
                        const float* __restrict__ bias, float* __restrict__ bnp) {
    int t = threadIdx.x;  // 128
    float mu = stats[t] * (1.0f / NN);
    float var = stats[128 + t] * (1.0f / NN) - mu * mu;
    float sc = scale[t] * rsqrtf(var + BN_EPS);
    bnp[t] = sc;
    bnp[128 + t] = bias[t] - mu * sc;
}

__global__ __launch_bounds__(256) void bn_relu(const float* __restrict__ Hp,
                                               const float* __restrict__ bnp,
                                               float* __restrict__ Hn) {
    const int total = NN * HD / 4;
    for (int i = blockIdx.x * blockDim.x + threadIdx.x; i < total; i += gridDim.x * blockDim.x) {
        int mb = (i & 31) * 4;
        float4 v = reinterpret_cast<const float4*>(Hp)[i];
        float4 sc = *reinterpret_cast<const float4*>(&bnp[mb]);
        float4 bi = *reinterpret_cast<const float4*>(&bnp[128 + mb]);
        v.x = fmaxf(v.x * sc.x + bi.x, 0.f);
        v.y = fmaxf(v.y * sc.y + bi.y, 0.f);
        v.z = fmaxf(v.z * sc.z + bi.z, 0.f);
        v.w = fmaxf(v.w * sc.w + bi.w, 0.f);
        reinterpret_cast<float4*>(Hn)[i] = v;
    }
}

// ---------------- aggregation: agg[n] = invdeg[n] * sum_{s in adj[n]} h[s] ----------------
__global__ __launch_bounds__(256) void agg_kernel(const float* __restrict__ H,
                                                  const int* __restrict__ adj,
                                                  const int* __restrict__ rowptr,
                                                  const float* __restrict__ invdeg,
                                                  float* __restrict__ A) {
    int node = blockIdx.x * 4 + (threadIdx.x >> 6);
    if (node >= NN) return;
    int lane = threadIdx.x & 63;
    int b = rowptr[node], e = rowptr[node + 1];
    float ax = 0.f, ay = 0.f;
    for (int i = b; i < e; ++i) {
        int s = adj[i];
        float2 v = *reinterpret_cast<const float2*>(&H[s * HD + lane * 2]);
        ax += v.x; ay += v.y;
    }
    float id = invdeg[node];
    float2 o; o.x = ax * id; o.y = ay * id;
    *reinterpret_cast<float2*>(&A[node * HD + lane * 2]) = o;
}

// ---------------- output GEMM: out[n,c] = sum_k H[n,k]*W[c,k] + b[c] ----------------
__global__ __launch_bounds__(256) void out_gemm(const float* __restrict__ H,
                                                const float* __restrict__ W,
                                                const float* __restrict__ B,
                                                float* __restrict__ out) {
    __shared__ float wlds[NCLS * 132];
    __shared__ float xlds[6 * HD];
    int t = threadIdx.x;
    for (int j = t; j < NCLS * HD; j += 256) {
        int c = j >> 7, k = j & 127;
        wlds[c * 132 + k] = W[j];
    }
    __syncthreads();
    int r = t / NCLS, c = t % NCLS;
    bool act = t < 6 * NCLS;
    float bv = act ? B[c] : 0.f;
    const int NT = (NN + 5) / 6;
    for (int tile = blockIdx.x; tile < NT; tile += gridDim.x) {
        int r0 = tile * 6;
        __syncthreads();
        int lim = (NN - r0) * HD;
        if (lim > 6 * HD) lim = 6 * HD;
        for (int j = t; j < 6 * HD; j += 256) xlds[j] = (j < lim) ? H[r0 * HD + j] : 0.f;
        __syncthreads();
        if (!act) continue;
        int row = r0 + r;
        if (row < NN) {
            float acc = 0.f;
#pragma unroll
            for (int kk = 0; kk < HD; kk += 4) {
                float4 w = *reinterpret_cast<float4*>(&wlds[c * 132 + kk]);
                float4 xv = *reinterpret_cast<float4*>(&xlds[r * HD + kk]);
                acc += w.x * xv.x + w.y * xv.y + w.z * xv.z + w.w * xv.w;
            }
            out[row * NCLS + c] = acc + bv;
        }
    }
}

extern "C" void kernel_launch(void* const* d_in, const int* in_sizes, int n_in,
                              void* d_out, int out_size, void* d_ws, size_t ws_size,
                              hipStream_t stream) {
    const float* x = (const float*)d_in[0];
    const void* ei = d_in[1];
    const float* fc0_w = (const float*)d_in[2];
    const float* fc0_b = (const float*)d_in[3];
    const float* bn_scale = (const float*)d_in[4];
    const float* bn_bias = (const float*)d_in[5];
    const float* lin_l = (const float*)d_in[6];
    const float* lin_r = (const float*)d_in[7];
    const float* W_w = (const float*)d_in[8];
    const float* W_b = (const float*)d_in[9];
    const float* out_w = (const float*)d_in[10];
    const float* out_b = (const float*)d_in[11];
    float* out = (float*)d_out;

    // ---- workspace carve-up (256B aligned) ----
    char* p = (char*)d_ws;
    auto alloc = [&](size_t bytes) -> void* {
        void* r = (void*)p;
        p += (bytes + 255) & ~(size_t)255;
        return r;
    };
    int* deg = (int*)alloc(NN * 4);
    int* cursor = (int*)alloc(NN * 4);
    float* stats = (float*)alloc(3 * 256 * 4);   // [3][sum128|sumsq128]
    int* eflag = (int*)alloc(256);
    size_t ctrl_bytes = (size_t)(p - (char*)d_ws);
    int* esrc = (int*)alloc(EE * 4);
    int* edst = (int*)alloc(EE * 4);
    int* rowptr = (int*)alloc((NN + 1) * 4);
    float* invdeg = (float*)alloc(NN * 4);
    int* adj = (int*)alloc(EE * 4);
    float* bnp = (float*)alloc(3 * 256 * 4);     // [3][scale128|bias128]
    float* Wc = (float*)alloc(4 * HD * HD * 4);  // [layer][l/r][128][128]
    float* hpre = (float*)alloc((size_t)NN * HD * 4);
    float* h = (float*)alloc((size_t)NN * HD * 4);
    float* agg = (float*)alloc((size_t)NN * HD * 4);

    // zero accumulators (deg, cursor, stats, eflag contiguous at ws start)
    hipMemsetAsync(d_ws, 0, ctrl_bytes, stream);

    // edge decode (robust to int32 vs int64 device layout)
    detect_kernel<<<1, 256, 0, stream>>>(ei, eflag);
    decode_kernel<<<1250, 512, 0, stream>>>(ei, eflag, esrc, edst);

    // graph build
    deg_kernel<<<1250, 512, 0, stream>>>(edst, deg);
    scan_kernel<<<1, 1024, 0, stream>>>(deg, rowptr, invdeg);
    fill_kernel<<<1250, 512, 0, stream>>>(esrc, edst, rowptr, cursor, adj);

    // combined weights
    combine_w<<<dim3(HD, 4), HD, 0, stream>>>(W_w, lin_l, lin_r, Wc);

    // fc0 + stats0
    gemm128<false, true><<<512, 256, 0, stream>>>(x, fc0_w, fc0_b, hpre, stats);
    bn_fold<<<1, 128, 0, stream>>>(stats, bn_scale, bn_bias, bnp);
    bn_relu<<<2048, 256, 0, stream>>>(hpre, bnp, h);

    for (int layer = 0; layer < 2; ++layer) {
        agg_kernel<<<NN / 4, 256, 0, stream>>>(h, adj, rowptr, invdeg, agg);
        const float* Wl = Wc + (size_t)(layer * 2 + 0) * HD * HD;
        const float* Wr = Wc + (size_t)(layer * 2 + 1) * HD * HD;
        float* st = stats + (layer + 1) * 256;
        gemm128<false, false><<<512, 256, 0, stream>>>(agg, Wl, nullptr, hpre, nullptr);
        gemm128<true, true><<<512, 256, 0, stream>>>(h, Wr, W_b, hpre, st);
        float* bp = bnp + (layer + 1) * 256;
        bn_fold<<<1, 128, 0, stream>>>(st, bn_scale + (layer + 1) * HD, bn_bias + (layer + 1) * HD, bp);
        bn_relu<<<2048, 256, 0, stream>>>(hpre, bp, h);
    }

    out_gemm<<<512, 256, 0, stream>>>(h, out_w, out_b, out);
}

// Round 3
// 585.284 us; speedup vs baseline: 1.1516x; 1.1516x over previous
//
#include <hip/hip_runtime.h>
#include <hip/hip_bf16.h>

#define NN 50000
#define EE 640000
#define HD 128
#define NCLS 40
#define BN_EPS 1e-5f
#define NTILE 782  // ceil(NN/64)

typedef short bf16x8 __attribute__((ext_vector_type(8)));
typedef float f32x4 __attribute__((ext_vector_type(4)));

__device__ __forceinline__ short f2bf(float f) {
    __hip_bfloat16 h = __float2bfloat16(f);
    return *reinterpret_cast<short*>(&h);
}
__device__ __forceinline__ float bflo(unsigned int v) { return __uint_as_float(v << 16); }
__device__ __forceinline__ float bfhi(unsigned int v) { return __uint_as_float(v & 0xffff0000u); }

// ---------------- edge_index width detect + decode (+degree count) ----------------
__global__ void detect_kernel(const void* __restrict__ ei, int* __restrict__ flag) {
    int t = threadIdx.x;  // 256
    const long long* p = (const long long*)ei;
    long long v = p[(size_t)t * (EE / 256)];
    if (v < 0 || v >= NN) atomicOr(flag, 1);  // flag=1 -> int32 data
}

__global__ void decode_deg_kernel(const void* __restrict__ ei, const int* __restrict__ flag,
                                  int* __restrict__ src, int* __restrict__ dst,
                                  int* __restrict__ deg) {
    bool narrow = (*flag != 0);
    for (int e = blockIdx.x * blockDim.x + threadIdx.x; e < EE; e += gridDim.x * blockDim.x) {
        int s, d;
        if (narrow) {
            const int* p = (const int*)ei;
            s = p[e]; d = p[EE + e];
        } else {
            const long long* p = (const long long*)ei;
            s = (int)p[e]; d = (int)p[EE + e];
        }
        src[e] = s;
        dst[e] = d;
        atomicAdd(&deg[d], 1);
    }
}

// ---------------- parallel scan: deg -> rowptr, invdeg ----------------
__global__ void deg_blocksum(const int* __restrict__ deg, int* __restrict__ bsum) {
    int i = blockIdx.x * 256 + threadIdx.x;
    int d = (i < NN) ? deg[i] : 0;
#pragma unroll
    for (int o = 32; o; o >>= 1) d += __shfl_down(d, o);
    __shared__ int ws[4];
    if ((threadIdx.x & 63) == 0) ws[threadIdx.x >> 6] = d;
    __syncthreads();
    if (threadIdx.x == 0) bsum[blockIdx.x] = ws[0] + ws[1] + ws[2] + ws[3];
}

__global__ void scan_bsums(const int* __restrict__ bsum, int* __restrict__ boff) {
    __shared__ int s[256];
    int t = threadIdx.x;
    int v = (t < 196) ? bsum[t] : 0;
    s[t] = v;
    __syncthreads();
    for (int o = 1; o < 256; o <<= 1) {
        int u = (t >= o) ? s[t - o] : 0;
        __syncthreads();
        s[t] += u;
        __syncthreads();
    }
    if (t < 196) boff[t] = s[t] - v;  // exclusive
}

__global__ void rowptr_fill(const int* __restrict__ deg, const int* __restrict__ boff,
                            int* __restrict__ rowptr, float* __restrict__ invdeg) {
    int b = blockIdx.x, t = threadIdx.x, i = b * 256 + t;
    int d = (i < NN) ? deg[i] : 0;
    __shared__ int s[256];
    s[t] = d;
    __syncthreads();
    for (int o = 1; o < 256; o <<= 1) {
        int u = (t >= o) ? s[t - o] : 0;
        __syncthreads();
        s[t] += u;
        __syncthreads();
    }
    int excl = s[t] - d + boff[b];
    if (i < NN) {
        rowptr[i] = excl;
        invdeg[i] = 1.0f / (float)(d > 1 ? d : 1);
        if (i == NN - 1) rowptr[NN] = excl + d;
    }
}

__global__ void fill_kernel(const int* __restrict__ src, const int* __restrict__ dst,
                            const int* __restrict__ rowptr, int* __restrict__ cursor,
                            int* __restrict__ adj) {
    for (int e = blockIdx.x * blockDim.x + threadIdx.x; e < EE; e += gridDim.x * blockDim.x) {
        int d = dst[e];
        int pos = atomicAdd(&cursor[d], 1);
        adj[rowptr[d] + pos] = src[e];
    }
}

// ---------------- combined weights: Wc[which] = W_w @ lin_{l/r}[layer] (fp32) ----------------
__global__ void combine_w(const float* __restrict__ Ww, const float* __restrict__ linl,
                          const float* __restrict__ linr, float* __restrict__ Wc) {
    int k = threadIdx.x;
    int m = blockIdx.x;
    int which = blockIdx.y;  // layer = which>>1, l/r = which&1
    const float* lin = ((which & 1) ? linr : linl) + (which >> 1) * HD * HD;
    __shared__ float wrow[HD];
    wrow[k] = Ww[m * HD + k];
    __syncthreads();
    float acc = 0.f;
    for (int j = 0; j < HD; ++j) acc += wrow[j] * lin[j * HD + k];
    Wc[which * HD * HD + m * HD + k] = acc;
}

// ---------------- MFMA GEMM: Y[n,m] = sum_k X[n,k]*W[m,k] (+bias)(+=Y)(+stats) ----------------
// B-fragments (whole 128x128 weight) held in registers; A streamed from global.
template <typename AT, bool ACC, bool STATS>
__global__ __launch_bounds__(256, 2) void gemm_mfma(const AT* __restrict__ X,
                                                    const float* __restrict__ W,
                                                    const float* __restrict__ bias,
                                                    float* __restrict__ Y,
                                                    float* __restrict__ stats) {
    int t = threadIdx.x;
    int l = t & 63, wv = t >> 6;
    int lr = l & 15, lg = l >> 4;

    bf16x8 bfrag[8][4];
#pragma unroll
    for (int c = 0; c < 8; ++c)
#pragma unroll
        for (int kk = 0; kk < 4; ++kk) {
            const float* wp = W + (c * 16 + lr) * HD + kk * 32 + lg * 8;
            float4 w0 = *reinterpret_cast<const float4*>(wp);
            float4 w1 = *reinterpret_cast<const float4*>(wp + 4);
            bf16x8 f;
            f[0] = f2bf(w0.x); f[1] = f2bf(w0.y); f[2] = f2bf(w0.z); f[3] = f2bf(w0.w);
            f[4] = f2bf(w1.x); f[5] = f2bf(w1.y); f[6] = f2bf(w1.z); f[7] = f2bf(w1.w);
            bfrag[c][kk] = f;
        }
    float bv[8];
#pragma unroll
    for (int c = 0; c < 8; ++c) bv[c] = bias ? bias[c * 16 + lr] : 0.f;

    float ss[8] = {0, 0, 0, 0, 0, 0, 0, 0}, sq[8] = {0, 0, 0, 0, 0, 0, 0, 0};

    for (int tile = blockIdx.x; tile < NTILE; tile += gridDim.x) {
        int r0 = tile * 64 + wv * 16;
        int rl = r0 + lr;
        if (rl > NN - 1) rl = NN - 1;
        f32x4 acc[8] = {};
#pragma unroll
        for (int kk = 0; kk < 4; ++kk) {
            bf16x8 af;
            if constexpr (sizeof(AT) == 4) {  // fp32 A source
                const float* xp = (const float*)X + (size_t)rl * HD + kk * 32 + lg * 8;
                float4 a0 = *reinterpret_cast<const float4*>(xp);
                float4 a1 = *reinterpret_cast<const float4*>(xp + 4);
                af[0] = f2bf(a0.x); af[1] = f2bf(a0.y); af[2] = f2bf(a0.z); af[3] = f2bf(a0.w);
                af[4] = f2bf(a1.x); af[5] = f2bf(a1.y); af[6] = f2bf(a1.z); af[7] = f2bf(a1.w);
            } else {  // bf16 (stored as short)
                af = *reinterpret_cast<const bf16x8*>((const short*)X + (size_t)rl * HD + kk * 32 + lg * 8);
            }
#pragma unroll
            for (int c = 0; c < 8; ++c)
                acc[c] = __builtin_amdgcn_mfma_f32_16x16x32_bf16(af, bfrag[c][kk], acc[c], 0, 0, 0);
        }
#pragma unroll
        for (int c = 0; c < 8; ++c) {
            int col = c * 16 + lr;
#pragma unroll
            for (int r = 0; r < 4; ++r) {
                int row = r0 + lg * 4 + r;
                if (row < NN) {
                    float y = acc[c][r] + bv[c];
                    float* yp = &Y[(size_t)row * HD + col];
                    if (ACC) y += *yp;
                    *yp = y;
                    if (STATS) { ss[c] += y; sq[c] += y * y; }
                }
            }
        }
    }

    if (STATS) {
        __shared__ float s1[HD], s2[HD];
        if (t < HD) { s1[t] = 0.f; s2[t] = 0.f; }
        __syncthreads();
#pragma unroll
        for (int c = 0; c < 8; ++c) {
            atomicAdd(&s1[c * 16 + lr], ss[c]);
            atomicAdd(&s2[c * 16 + lr], sq[c]);
        }
        __syncthreads();
        if (t < HD) {
            atomicAdd(&stats[t], s1[t]);
            atomicAdd(&stats[HD + t], s2[t]);
        }
    }
}

// ---------------- BN fold + apply (writes bf16 h) ----------------
__global__ void bn_fold(const float* __restrict__ stats, const float* __restrict__ scale,
                        const float* __restrict__ bias, float* __restrict__ bnp) {
    int t = threadIdx.x;  // 128
    float mu = stats[t] * (1.0f / NN);
    float var = stats[HD + t] * (1.0f / NN) - mu * mu;
    float sc = scale[t] * rsqrtf(var + BN_EPS);
    bnp[t] = sc;
    bnp[HD + t] = bias[t] - mu * sc;
}

__global__ __launch_bounds__(256) void bn_relu(const float* __restrict__ Hp,
                                               const float* __restrict__ bnp,
                                               ushort* __restrict__ Hb) {
    int i = blockIdx.x * 256 + threadIdx.x;  // one thread per 8 features
    if (i >= NN * HD / 8) return;
    int mb = (i & 15) * 8;
    const float4* hp = reinterpret_cast<const float4*>(Hp) + (size_t)i * 2;
    float4 a = hp[0], b = hp[1];
    float4 sa = *reinterpret_cast<const float4*>(&bnp[mb]);
    float4 sb = *reinterpret_cast<const float4*>(&bnp[mb + 4]);
    float4 ba = *reinterpret_cast<const float4*>(&bnp[HD + mb]);
    float4 bb = *reinterpret_cast<const float4*>(&bnp[HD + mb + 4]);
    float v0 = fmaxf(a.x * sa.x + ba.x, 0.f);
    float v1 = fmaxf(a.y * sa.y + ba.y, 0.f);
    float v2 = fmaxf(a.z * sa.z + ba.z, 0.f);
    float v3 = fmaxf(a.w * sa.w + ba.w, 0.f);
    float v4 = fmaxf(b.x * sb.x + bb.x, 0.f);
    float v5 = fmaxf(b.y * sb.y + bb.y, 0.f);
    float v6 = fmaxf(b.z * sb.z + bb.z, 0.f);
    float v7 = fmaxf(b.w * sb.w + bb.w, 0.f);
    uint4 o;
    o.x = (unsigned)(unsigned short)f2bf(v0) | ((unsigned)(unsigned short)f2bf(v1) << 16);
    o.y = (unsigned)(unsigned short)f2bf(v2) | ((unsigned)(unsigned short)f2bf(v3) << 16);
    o.z = (unsigned)(unsigned short)f2bf(v4) | ((unsigned)(unsigned short)f2bf(v5) << 16);
    o.w = (unsigned)(unsigned short)f2bf(v6) | ((unsigned)(unsigned short)f2bf(v7) << 16);
    *reinterpret_cast<uint4*>(Hb + (size_t)i * 8) = o;
}

// ---------------- aggregation (bf16 in/out): agg[n] = invdeg[n]*sum h[adj] ----------------
__global__ __launch_bounds__(256) void agg_kernel(const ushort* __restrict__ H,
                                                  const int* __restrict__ adj,
                                                  const int* __restrict__ rowptr,
                                                  const float* __restrict__ invdeg,
                                                  ushort* __restrict__ A) {
    int node = blockIdx.x * 4 + (threadIdx.x >> 6);
    if (node >= NN) return;
    int lane = threadIdx.x & 63;
    int b = rowptr[node], e = rowptr[node + 1];
    float ax = 0.f, ay = 0.f;
    for (int i = b; i < e; ++i) {
        int s = adj[i];
        unsigned int v = *reinterpret_cast<const unsigned int*>(&H[(size_t)s * HD + lane * 2]);
        ax += bflo(v);
        ay += bfhi(v);
    }
    float id = invdeg[node];
    unsigned int lo = (unsigned short)f2bf(ax * id);
    unsigned int hi = (unsigned short)f2bf(ay * id);
    *reinterpret_cast<unsigned int*>(&A[(size_t)node * HD + lane * 2]) = lo | (hi << 16);
}

// ---------------- output GEMM (fp32 dot): out[n,c] = sum_k h[n,k]*W[c,k] + b[c] ----------------
__global__ __launch_bounds__(256) void out_gemm(const ushort* __restrict__ H,
                                                const float* __restrict__ W,
                                                const float* __restrict__ B,
                                                float* __restrict__ out) {
    __shared__ float wlds[NCLS * 132];
    __shared__ float xlds[6 * HD];
    int t = threadIdx.x;
    for (int j = t; j < NCLS * HD; j += 256) {
        int c = j >> 7, k = j & 127;
        wlds[c * 132 + k] = W[j];
    }
    __syncthreads();
    int r = t / NCLS, c = t % NCLS;
    bool act = t < 6 * NCLS;
    float bv = act ? B[c] : 0.f;
    const int NT = (NN + 5) / 6;
    for (int tile = blockIdx.x; tile < NT; tile += gridDim.x) {
        int r0 = tile * 6;
        __syncthreads();
        const unsigned int* hp = reinterpret_cast<const unsigned int*>(H + (size_t)r0 * HD);
        for (int j = t; j < 3 * HD; j += 256) {  // 384 uints = 768 bf16
            unsigned int v = hp[j];
            xlds[j * 2] = bflo(v);
            xlds[j * 2 + 1] = bfhi(v);
        }
        __syncthreads();
        if (!act) continue;
        int row = r0 + r;
        if (row < NN) {
            float acc = 0.f;
#pragma unroll
            for (int kk = 0; kk < HD; kk += 4) {
                float4 w = *reinterpret_cast<float4*>(&wlds[c * 132 + kk]);
                float4 xv = *reinterpret_cast<float4*>(&xlds[r * HD + kk]);
                acc += w.x * xv.x + w.y * xv.y + w.z * xv.z + w.w * xv.w;
            }
            out[(size_t)row * NCLS + c] = acc + bv;
        }
    }
}

extern "C" void kernel_launch(void* const* d_in, const int* in_sizes, int n_in,
                              void* d_out, int out_size, void* d_ws, size_t ws_size,
                              hipStream_t stream) {
    const float* x = (const float*)d_in[0];
    const void* ei = d_in[1];
    const float* fc0_w = (const float*)d_in[2];
    const float* fc0_b = (const float*)d_in[3];
    const float* bn_scale = (const float*)d_in[4];
    const float* bn_bias = (const float*)d_in[5];
    const float* lin_l = (const float*)d_in[6];
    const float* lin_r = (const float*)d_in[7];
    const float* W_w = (const float*)d_in[8];
    const float* W_b = (const float*)d_in[9];
    const float* out_w = (const float*)d_in[10];
    const float* out_b = (const float*)d_in[11];
    float* out = (float*)d_out;

    // ---- workspace carve-up (256B aligned) ----
    char* p = (char*)d_ws;
    auto alloc = [&](size_t bytes) -> void* {
        void* r = (void*)p;
        p += (bytes + 255) & ~(size_t)255;
        return r;
    };
    int* deg = (int*)alloc(NN * 4);
    int* cursor = (int*)alloc(NN * 4);
    float* stats = (float*)alloc(3 * 256 * 4);  // [3][sum128|sumsq128]
    int* eflag = (int*)alloc(256);
    size_t ctrl_bytes = (size_t)(p - (char*)d_ws);
    int* esrc = (int*)alloc(EE * 4);
    int* edst = (int*)alloc(EE * 4);
    int* rowptr = (int*)alloc((NN + 1) * 4);
    float* invdeg = (float*)alloc(NN * 4);
    int* adj = (int*)alloc(EE * 4);
    int* bsum = (int*)alloc(256 * 4);
    int* boff = (int*)alloc(256 * 4);
    float* bnp = (float*)alloc(3 * 256 * 4);     // [3][scale128|bias128]
    float* Wc = (float*)alloc(4 * HD * HD * 4);  // [layer][l/r][128][128] fp32
    float* hpre = (float*)alloc((size_t)NN * HD * 4);
    ushort* hb = (ushort*)alloc((size_t)NN * HD * 2);
    ushort* aggb = (ushort*)alloc((size_t)NN * HD * 2);

    hipMemsetAsync(d_ws, 0, ctrl_bytes, stream);

    // edge decode + degree
    detect_kernel<<<1, 256, 0, stream>>>(ei, eflag);
    decode_deg_kernel<<<1250, 512, 0, stream>>>(ei, eflag, esrc, edst, deg);

    // parallel scan -> rowptr/invdeg, then CSR fill
    deg_blocksum<<<196, 256, 0, stream>>>(deg, bsum);
    scan_bsums<<<1, 256, 0, stream>>>(bsum, boff);
    rowptr_fill<<<196, 256, 0, stream>>>(deg, boff, rowptr, invdeg);
    fill_kernel<<<1250, 512, 0, stream>>>(esrc, edst, rowptr, cursor, adj);

    // combined weights
    combine_w<<<dim3(HD, 4), HD, 0, stream>>>(W_w, lin_l, lin_r, Wc);

    // fc0 + BN0 + ReLU
    gemm_mfma<float, false, true><<<NTILE, 256, 0, stream>>>(x, fc0_w, fc0_b, hpre, stats);
    bn_fold<<<1, 128, 0, stream>>>(stats, bn_scale, bn_bias, bnp);
    bn_relu<<<3125, 256, 0, stream>>>(hpre, bnp, hb);

    for (int layer = 0; layer < 2; ++layer) {
        agg_kernel<<<(NN + 3) / 4, 256, 0, stream>>>(hb, adj, rowptr, invdeg, aggb);
        const float* Wl = Wc + (size_t)(layer * 2 + 0) * HD * HD;
        const float* Wr = Wc + (size_t)(layer * 2 + 1) * HD * HD;
        float* st = stats + (layer + 1) * 256;
        gemm_mfma<short, false, false><<<NTILE, 256, 0, stream>>>((const short*)aggb, Wl, nullptr, hpre, nullptr);
        gemm_mfma<short, true, true><<<NTILE, 256, 0, stream>>>((const short*)hb, Wr, W_b, hpre, st);
        float* bp = bnp + (layer + 1) * 256;
        bn_fold<<<1, 128, 0, stream>>>(st, bn_scale + (layer + 1) * HD, bn_bias + (layer + 1) * HD, bp);
        bn_relu<<<3125, 256, 0, stream>>>(hpre, bp, hb);
    }

    out_gemm<<<512, 256, 0, stream>>>(hb, out_w, out_b, out);
}

// Round 4
// 487.664 us; speedup vs baseline: 1.3821x; 1.2002x over previous
//
#include <hip/hip_runtime.h>
#include <hip/hip_bf16.h>

#define NN 50000
#define EE 640000
#define HD 128
#define NCLS 40
#define BN_EPS 1e-5f
#define NTILE 782  // ceil(NN/64)

typedef short bf16x8 __attribute__((ext_vector_type(8)));
typedef float f32x4 __attribute__((ext_vector_type(4)));

__device__ __forceinline__ short f2bf(float f) {
    __hip_bfloat16 h = __float2bfloat16(f);
    return *reinterpret_cast<short*>(&h);
}
__device__ __forceinline__ float bflo(unsigned int v) { return __uint_as_float(v << 16); }
__device__ __forceinline__ float bfhi(unsigned int v) { return __uint_as_float(v & 0xffff0000u); }

// ---------------- edge_index width detect + decode (+degree count) ----------------
__global__ void detect_kernel(const void* __restrict__ ei, int* __restrict__ flag) {
    int t = threadIdx.x;  // 256
    const long long* p = (const long long*)ei;
    long long v = p[(size_t)t * (EE / 256)];
    if (v < 0 || v >= NN) atomicOr(flag, 1);  // flag=1 -> int32 data
}

__global__ void decode_deg_kernel(const void* __restrict__ ei, const int* __restrict__ flag,
                                  int* __restrict__ src, int* __restrict__ dst,
                                  int* __restrict__ deg) {
    bool narrow = (*flag != 0);
    for (int e = blockIdx.x * blockDim.x + threadIdx.x; e < EE; e += gridDim.x * blockDim.x) {
        int s, d;
        if (narrow) {
            const int* p = (const int*)ei;
            s = p[e]; d = p[EE + e];
        } else {
            const long long* p = (const long long*)ei;
            s = (int)p[e]; d = (int)p[EE + e];
        }
        src[e] = s;
        dst[e] = d;
        atomicAdd(&deg[d], 1);
    }
}

// ---------------- parallel scan: deg -> rowptr, invdeg ----------------
__global__ void deg_blocksum(const int* __restrict__ deg, int* __restrict__ bsum) {
    int i = blockIdx.x * 256 + threadIdx.x;
    int d = (i < NN) ? deg[i] : 0;
#pragma unroll
    for (int o = 32; o; o >>= 1) d += __shfl_down(d, o);
    __shared__ int ws[4];
    if ((threadIdx.x & 63) == 0) ws[threadIdx.x >> 6] = d;
    __syncthreads();
    if (threadIdx.x == 0) bsum[blockIdx.x] = ws[0] + ws[1] + ws[2] + ws[3];
}

__global__ void scan_bsums(const int* __restrict__ bsum, int* __restrict__ boff) {
    __shared__ int s[256];
    int t = threadIdx.x;
    int v = (t < 196) ? bsum[t] : 0;
    s[t] = v;
    __syncthreads();
    for (int o = 1; o < 256; o <<= 1) {
        int u = (t >= o) ? s[t - o] : 0;
        __syncthreads();
        s[t] += u;
        __syncthreads();
    }
    if (t < 196) boff[t] = s[t] - v;  // exclusive
}

__global__ void rowptr_fill(const int* __restrict__ deg, const int* __restrict__ boff,
                            int* __restrict__ rowptr, float* __restrict__ invdeg) {
    int b = blockIdx.x, t = threadIdx.x, i = b * 256 + t;
    int d = (i < NN) ? deg[i] : 0;
    __shared__ int s[256];
    s[t] = d;
    __syncthreads();
    for (int o = 1; o < 256; o <<= 1) {
        int u = (t >= o) ? s[t - o] : 0;
        __syncthreads();
        s[t] += u;
        __syncthreads();
    }
    int excl = s[t] - d + boff[b];
    if (i < NN) {
        rowptr[i] = excl;
        invdeg[i] = 1.0f / (float)(d > 1 ? d : 1);
        if (i == NN - 1) rowptr[NN] = excl + d;
    }
}

__global__ void fill_kernel(const int* __restrict__ src, const int* __restrict__ dst,
                            const int* __restrict__ rowptr, int* __restrict__ cursor,
                            int* __restrict__ adj) {
    for (int e = blockIdx.x * blockDim.x + threadIdx.x; e < EE; e += gridDim.x * blockDim.x) {
        int d = dst[e];
        int pos = atomicAdd(&cursor[d], 1);
        adj[rowptr[d] + pos] = src[e];
    }
}

// ---------------- combined weights: Wc[which] = W_w @ lin_{l/r}[layer] (fp32) ----------------
__global__ void combine_w(const float* __restrict__ Ww, const float* __restrict__ linl,
                          const float* __restrict__ linr, float* __restrict__ Wc) {
    int k = threadIdx.x;
    int m = blockIdx.x;
    int which = blockIdx.y;  // layer = which>>1, l/r = which&1
    const float* lin = ((which & 1) ? linr : linl) + (which >> 1) * HD * HD;
    __shared__ float wrow[HD];
    wrow[k] = Ww[m * HD + k];
    __syncthreads();
    float acc = 0.f;
    for (int j = 0; j < HD; ++j) acc += wrow[j] * lin[j * HD + k];
    Wc[which * HD * HD + m * HD + k] = acc;
}

// ---------------- MFMA GEMM (swapped operands, wave-sliced columns) ----------------
// Y[n,m] = sum_k A1[n,k]*W1[m,k] (+ A2[n,k]*W2[m,k]); per-column stats fused.
// No bias (BatchNorm cancels additive per-column constants).
// Wave wv owns cols [wv*32, wv*32+32). mfma(a=Wfrag, b=Xfrag): D col=lane&15 -> X row,
// D rows (reg) -> 4 consecutive Y cols => coalesced f32x4 stores.
template <bool DUAL, bool F32A>
__global__ __launch_bounds__(256) void gemm_mfma(const void* __restrict__ A1,
                                                 const void* __restrict__ A2,
                                                 const float* __restrict__ W1,
                                                 const float* __restrict__ W2,
                                                 float* __restrict__ Y,
                                                 float* __restrict__ stats) {
    int t = threadIdx.x;
    int l = t & 63, wv = t >> 6;
    int lr = l & 15, lg = l >> 4;

    // B-operand fragments (weights), wave's column slice: c_global = wv*2 + cc
    bf16x8 bf1[2][4], bf2[2][4];
#pragma unroll
    for (int cc = 0; cc < 2; ++cc)
#pragma unroll
        for (int kk = 0; kk < 4; ++kk) {
            int wrow = (wv * 2 + cc) * 16 + lr;
            const float* wp = W1 + wrow * HD + kk * 32 + lg * 8;
            float4 w0 = *reinterpret_cast<const float4*>(wp);
            float4 w1 = *reinterpret_cast<const float4*>(wp + 4);
            bf16x8 f;
            f[0] = f2bf(w0.x); f[1] = f2bf(w0.y); f[2] = f2bf(w0.z); f[3] = f2bf(w0.w);
            f[4] = f2bf(w1.x); f[5] = f2bf(w1.y); f[6] = f2bf(w1.z); f[7] = f2bf(w1.w);
            bf1[cc][kk] = f;
            if (DUAL) {
                const float* wq = W2 + wrow * HD + kk * 32 + lg * 8;
                float4 v0 = *reinterpret_cast<const float4*>(wq);
                float4 v1 = *reinterpret_cast<const float4*>(wq + 4);
                bf16x8 g;
                g[0] = f2bf(v0.x); g[1] = f2bf(v0.y); g[2] = f2bf(v0.z); g[3] = f2bf(v0.w);
                g[4] = f2bf(v1.x); g[5] = f2bf(v1.y); g[6] = f2bf(v1.z); g[7] = f2bf(v1.w);
                bf2[cc][kk] = g;
            }
        }

    f32x4 ss[2] = {}, sq[2] = {};

    for (int tile = blockIdx.x; tile < NTILE; tile += gridDim.x) {
        int rbase = tile * 64;
        f32x4 acc[4][2] = {};
#pragma unroll
        for (int kk = 0; kk < 4; ++kk) {
            bf16x8 a1[4], a2[4];
#pragma unroll
            for (int rf = 0; rf < 4; ++rf) {
                int rl = rbase + rf * 16 + lr;
                if (rl > NN - 1) rl = NN - 1;
                size_t off = (size_t)rl * HD + kk * 32 + lg * 8;
                if constexpr (F32A) {
                    const float* xp = (const float*)A1 + off;
                    float4 x0 = *reinterpret_cast<const float4*>(xp);
                    float4 x1 = *reinterpret_cast<const float4*>(xp + 4);
                    bf16x8 f;
                    f[0] = f2bf(x0.x); f[1] = f2bf(x0.y); f[2] = f2bf(x0.z); f[3] = f2bf(x0.w);
                    f[4] = f2bf(x1.x); f[5] = f2bf(x1.y); f[6] = f2bf(x1.z); f[7] = f2bf(x1.w);
                    a1[rf] = f;
                } else {
                    a1[rf] = *reinterpret_cast<const bf16x8*>((const short*)A1 + off);
                }
                if (DUAL) a2[rf] = *reinterpret_cast<const bf16x8*>((const short*)A2 + off);
            }
#pragma unroll
            for (int cc = 0; cc < 2; ++cc)
#pragma unroll
                for (int rf = 0; rf < 4; ++rf) {
                    acc[rf][cc] = __builtin_amdgcn_mfma_f32_16x16x32_bf16(bf1[cc][kk], a1[rf], acc[rf][cc], 0, 0, 0);
                    if (DUAL)
                        acc[rf][cc] = __builtin_amdgcn_mfma_f32_16x16x32_bf16(bf2[cc][kk], a2[rf], acc[rf][cc], 0, 0, 0);
                }
        }
        // store + stats: lane holds row = rbase+rf*16+lr, cols (wv*2+cc)*16 + lg*4 + 0..3
#pragma unroll
        for (int rf = 0; rf < 4; ++rf) {
            int row = rbase + rf * 16 + lr;
            if (row < NN) {
#pragma unroll
                for (int cc = 0; cc < 2; ++cc) {
                    f32x4 v = acc[rf][cc];
                    *reinterpret_cast<f32x4*>(&Y[(size_t)row * HD + (wv * 2 + cc) * 16 + lg * 4]) = v;
                    ss[cc] += v;
                    sq[cc] += v * v;
                }
            }
        }
    }

    // reduce stats over the 16 lanes sharing lg (different rows, same cols)
#pragma unroll
    for (int cc = 0; cc < 2; ++cc)
#pragma unroll
        for (int j = 0; j < 4; ++j) {
            float a = ss[cc][j], b = sq[cc][j];
#pragma unroll
            for (int m = 1; m < 16; m <<= 1) {
                a += __shfl_xor(a, m);
                b += __shfl_xor(b, m);
            }
            if (lr == 0) {
                int col = (wv * 2 + cc) * 16 + lg * 4 + j;
                atomicAdd(&stats[col], a);
                atomicAdd(&stats[HD + col], b);
            }
        }
}

// ---------------- BN fold + apply (writes bf16 h) ----------------
__global__ void bn_fold(const float* __restrict__ stats, const float* __restrict__ scale,
                        const float* __restrict__ bias, float* __restrict__ bnp) {
    int t = threadIdx.x;  // 128
    float mu = stats[t] * (1.0f / NN);
    float var = stats[HD + t] * (1.0f / NN) - mu * mu;
    float sc = scale[t] * rsqrtf(var + BN_EPS);
    bnp[t] = sc;
    bnp[HD + t] = bias[t] - mu * sc;
}

__global__ __launch_bounds__(256) void bn_relu(const float* __restrict__ Hp,
                                               const float* __restrict__ bnp,
                                               ushort* __restrict__ Hb) {
    int i = blockIdx.x * 256 + threadIdx.x;  // one thread per 8 features
    if (i >= NN * HD / 8) return;
    int mb = (i & 15) * 8;
    const float4* hp = reinterpret_cast<const float4*>(Hp) + (size_t)i * 2;
    float4 a = hp[0], b = hp[1];
    float4 sa = *reinterpret_cast<const float4*>(&bnp[mb]);
    float4 sb = *reinterpret_cast<const float4*>(&bnp[mb + 4]);
    float4 ba = *reinterpret_cast<const float4*>(&bnp[HD + mb]);
    float4 bb = *reinterpret_cast<const float4*>(&bnp[HD + mb + 4]);
    float v0 = fmaxf(a.x * sa.x + ba.x, 0.f);
    float v1 = fmaxf(a.y * sa.y + ba.y, 0.f);
    float v2 = fmaxf(a.z * sa.z + ba.z, 0.f);
    float v3 = fmaxf(a.w * sa.w + ba.w, 0.f);
    float v4 = fmaxf(b.x * sb.x + bb.x, 0.f);
    float v5 = fmaxf(b.y * sb.y + bb.y, 0.f);
    float v6 = fmaxf(b.z * sb.z + bb.z, 0.f);
    float v7 = fmaxf(b.w * sb.w + bb.w, 0.f);
    uint4 o;
    o.x = (unsigned)(unsigned short)f2bf(v0) | ((unsigned)(unsigned short)f2bf(v1) << 16);
    o.y = (unsigned)(unsigned short)f2bf(v2) | ((unsigned)(unsigned short)f2bf(v3) << 16);
    o.z = (unsigned)(unsigned short)f2bf(v4) | ((unsigned)(unsigned short)f2bf(v5) << 16);
    o.w = (unsigned)(unsigned short)f2bf(v6) | ((unsigned)(unsigned short)f2bf(v7) << 16);
    *reinterpret_cast<uint4*>(Hb + (size_t)i * 8) = o;
}

// ---------------- aggregation (bf16 in/out): agg[n] = invdeg[n]*sum h[adj] ----------------
__global__ __launch_bounds__(256) void agg_kernel(const ushort* __restrict__ H,
                                                  const int* __restrict__ adj,
                                                  const int* __restrict__ rowptr,
                                                  const float* __restrict__ invdeg,
                                                  ushort* __restrict__ A) {
    int node = blockIdx.x * 4 + (threadIdx.x >> 6);
    if (node >= NN) return;
    int lane = threadIdx.x & 63;
    int b = rowptr[node], e = rowptr[node + 1];
    float ax = 0.f, ay = 0.f;
    for (int i = b; i < e; ++i) {
        int s = adj[i];
        unsigned int v = *reinterpret_cast<const unsigned int*>(&H[(size_t)s * HD + lane * 2]);
        ax += bflo(v);
        ay += bfhi(v);
    }
    float id = invdeg[node];
    unsigned int lo = (unsigned short)f2bf(ax * id);
    unsigned int hi = (unsigned short)f2bf(ay * id);
    *reinterpret_cast<unsigned int*>(&A[(size_t)node * HD + lane * 2]) = lo | (hi << 16);
}

// ---------------- output GEMM (fp32 dot): out[n,c] = sum_k h[n,k]*W[c,k] + b[c] ----------------
__global__ __launch_bounds__(256) void out_gemm(const ushort* __restrict__ H,
                                                const float* __restrict__ W,
                                                const float* __restrict__ B,
                                                float* __restrict__ out) {
    __shared__ float wlds[NCLS * 132];
    __shared__ float xlds[6 * HD];
    int t = threadIdx.x;
    for (int j = t; j < NCLS * HD; j += 256) {
        int c = j >> 7, k = j & 127;
        wlds[c * 132 + k] = W[j];
    }
    __syncthreads();
    int r = t / NCLS, c = t % NCLS;
    bool act = t < 6 * NCLS;
    float bv = act ? B[c] : 0.f;
    const int NT = (NN + 5) / 6;
    for (int tile = blockIdx.x; tile < NT; tile += gridDim.x) {
        int r0 = tile * 6;
        __syncthreads();
        const unsigned int* hp = reinterpret_cast<const unsigned int*>(H + (size_t)r0 * HD);
        for (int j = t; j < 3 * HD; j += 256) {  // 384 uints = 768 bf16
            unsigned int v = hp[j];
            xlds[j * 2] = bflo(v);
            xlds[j * 2 + 1] = bfhi(v);
        }
        __syncthreads();
        if (!act) continue;
        int row = r0 + r;
        if (row < NN) {
            float acc = 0.f;
#pragma unroll
            for (int kk = 0; kk < HD; kk += 4) {
                float4 w = *reinterpret_cast<float4*>(&wlds[c * 132 + kk]);
                float4 xv = *reinterpret_cast<float4*>(&xlds[r * HD + kk]);
                acc += w.x * xv.x + w.y * xv.y + w.z * xv.z + w.w * xv.w;
            }
            out[(size_t)row * NCLS + c] = acc + bv;
        }
    }
}

extern "C" void kernel_launch(void* const* d_in, const int* in_sizes, int n_in,
                              void* d_out, int out_size, void* d_ws, size_t ws_size,
                              hipStream_t stream) {
    const float* x = (const float*)d_in[0];
    const void* ei = d_in[1];
    const float* fc0_w = (const float*)d_in[2];
    const float* bn_scale = (const float*)d_in[4];
    const float* bn_bias = (const float*)d_in[5];
    const float* lin_l = (const float*)d_in[6];
    const float* lin_r = (const float*)d_in[7];
    const float* W_w = (const float*)d_in[8];
    const float* out_w = (const float*)d_in[10];
    const float* out_b = (const float*)d_in[11];
    float* out = (float*)d_out;

    // ---- workspace carve-up (256B aligned) ----
    char* p = (char*)d_ws;
    auto alloc = [&](size_t bytes) -> void* {
        void* r = (void*)p;
        p += (bytes + 255) & ~(size_t)255;
        return r;
    };
    int* deg = (int*)alloc(NN * 4);
    int* cursor = (int*)alloc(NN * 4);
    float* stats = (float*)alloc(3 * 256 * 4);  // [3][sum128|sumsq128]
    int* eflag = (int*)alloc(256);
    size_t ctrl_bytes = (size_t)(p - (char*)d_ws);
    int* esrc = (int*)alloc(EE * 4);
    int* edst = (int*)alloc(EE * 4);
    int* rowptr = (int*)alloc((NN + 1) * 4);
    float* invdeg = (float*)alloc(NN * 4);
    int* adj = (int*)alloc(EE * 4);
    int* bsum = (int*)alloc(256 * 4);
    int* boff = (int*)alloc(256 * 4);
    float* bnp = (float*)alloc(3 * 256 * 4);     // [3][scale128|bias128]
    float* Wc = (float*)alloc(4 * HD * HD * 4);  // [layer][l/r][128][128] fp32
    float* hpre = (float*)alloc((size_t)NN * HD * 4);
    ushort* hb = (ushort*)alloc((size_t)NN * HD * 2);
    ushort* aggb = (ushort*)alloc((size_t)NN * HD * 2);

    hipMemsetAsync(d_ws, 0, ctrl_bytes, stream);

    // edge decode + degree
    detect_kernel<<<1, 256, 0, stream>>>(ei, eflag);
    decode_deg_kernel<<<1250, 512, 0, stream>>>(ei, eflag, esrc, edst, deg);

    // parallel scan -> rowptr/invdeg, then CSR fill
    deg_blocksum<<<196, 256, 0, stream>>>(deg, bsum);
    scan_bsums<<<1, 256, 0, stream>>>(bsum, boff);
    rowptr_fill<<<196, 256, 0, stream>>>(deg, boff, rowptr, invdeg);
    fill_kernel<<<1250, 512, 0, stream>>>(esrc, edst, rowptr, cursor, adj);

    // combined weights
    combine_w<<<dim3(HD, 4), HD, 0, stream>>>(W_w, lin_l, lin_r, Wc);

    // fc0 + BN0 + ReLU (fc0_b dropped: cancelled by BN)
    gemm_mfma<false, true><<<512, 256, 0, stream>>>(x, nullptr, fc0_w, nullptr, hpre, stats);
    bn_fold<<<1, 128, 0, stream>>>(stats, bn_scale, bn_bias, bnp);
    bn_relu<<<3125, 256, 0, stream>>>(hpre, bnp, hb);

    for (int layer = 0; layer < 2; ++layer) {
        agg_kernel<<<(NN + 3) / 4, 256, 0, stream>>>(hb, adj, rowptr, invdeg, aggb);
        const float* Wl = Wc + (size_t)(layer * 2 + 0) * HD * HD;
        const float* Wr = Wc + (size_t)(layer * 2 + 1) * HD * HD;
        float* st = stats + (layer + 1) * 256;
        // fused: hpre = aggb@Wl^T + hb@Wr^T, stats fused (W_b dropped: cancelled by BN)
        gemm_mfma<true, false><<<512, 256, 0, stream>>>(aggb, hb, Wl, Wr, hpre, st);
        float* bp = bnp + (layer + 1) * 256;
        bn_fold<<<1, 128, 0, stream>>>(st, bn_scale + (layer + 1) * HD, bn_bias + (layer + 1) * HD, bp);
        bn_relu<<<3125, 256, 0, stream>>>(hpre, bp, hb);
    }

    out_gemm<<<512, 256, 0, stream>>>(hb, out_w, out_b, out);
}